// Round 6
// baseline (304.835 us; speedup 1.0000x reference)
//
#include <hip/hip_runtime.h>
#include <hip/hip_bf16.h>

#define N_NODES 50000
#define N_EDGES 800000

#define ROW_TILES    391   // ceil(50000/128)
// k1 grid: 49 windows x 48 blocks. In each window: pos>>3 = o in 0..5;
// o in {2,5} -> hist block, o in {0,1,3,4} -> gemm quarter q of tile t=w*8+(b&7).
// All 4 quarters of a tile share b%8 (same XCD under round-robin) -> feature L2 reuse.
#define K1_BLOCKS    2352  // 49*48
#define WCONV_BLOCKS 512
#define SCAN_BLOCKS  196   // ceil(50000/256)
#define EDGE_BLOCKS  782

typedef __bf16 bf16x8_t __attribute__((ext_vector_type(8)));
typedef float  f32x4_t  __attribute__((ext_vector_type(4)));
typedef unsigned short u16x8 __attribute__((ext_vector_type(8)));
typedef unsigned int   u32x4 __attribute__((ext_vector_type(4)));

__device__ __forceinline__ unsigned short f2bf(float x) {
  __hip_bfloat16 h = __float2bfloat16(x);
  return __builtin_bit_cast(unsigned short, h);
}
__device__ __forceinline__ float bf2f(unsigned short u) {
  unsigned int v = ((unsigned int)u) << 16;
  return __builtin_bit_cast(float, v);
}
__device__ __forceinline__ unsigned int pk2(float lo, float hi) {
  return ((unsigned int)f2bf(hi) << 16) | (unsigned int)f2bf(lo);
}
__device__ __forceinline__ bf16x8_t cvt8(float4 lo, float4 hi) {
  u32x4 u;
  u.x = pk2(lo.x, lo.y); u.y = pk2(lo.z, lo.w);
  u.z = pk2(hi.x, hi.y); u.w = pk2(hi.z, hi.w);
  return __builtin_bit_cast(bf16x8_t, u);
}

// ------------- k0: W_self|W (f32, k-major) -> Bt (bf16, n-major) -------------
__global__ __launch_bounds__(256) void wconv_kernel(
    const float* __restrict__ Wself, const float* __restrict__ W,
    unsigned short* __restrict__ Bt)
{
  int idx = blockIdx.x * 256 + threadIdx.x;   // [512][256]
  int n = idx >> 8, k = idx & 255;
  float v = (n < 256) ? Wself[k * 256 + n] : W[k * 256 + (n - 256)];
  Bt[idx] = f2bf(v);
}

// ------------- k1: fused barrier-free GEMM + interleaved edge histogram -------------
// GEMM: zero LDS, zero __syncthreads. Each wave owns a 64x64 output sub-tile and
// streams MFMA fragments DIRECTLY from global (A: f32 L3-hot, cvt in-reg; B: bf16
// L2-hot 256KB). Fragment loads coalesce as 16 rows x 64B per half-wave.
__global__ __launch_bounds__(256, 4) void gemm_edge_kernel(
    const float* __restrict__ feature,       // [N][256] f32
    const unsigned short* __restrict__ Bt,   // [512][256] bf16 (n-major)
    const float* __restrict__ e_w, const int* __restrict__ src, const int* __restrict__ dst,
    int* __restrict__ cnt_in, int* __restrict__ cnt_out,
    unsigned char* __restrict__ rank8, float* __restrict__ out1,
    unsigned short* __restrict__ hs16,       // [N][256] bf16 (feature@Wself)
    unsigned char* __restrict__ y8)          // [N][256] fp8 e4m3 (feature@W, un-normalized)
{
  const int b   = blockIdx.x;
  const int tid = threadIdx.x;
  const int w   = b / 48;
  const int o   = (b % 48) >> 3;             // 0..5
  const int r   = b & 7;

  if (o == 2 || o == 5) {
    // -------- hist block: 1024 edges, 4 per thread, coalesced; NO scatter --------
    const int h = w * 16 + r + ((o == 5) ? 8 : 0);
    if (h >= EDGE_BLOCKS) return;
    const int e0 = h * 1024 + tid;
#pragma unroll
    for (int k = 0; k < 4; ++k) {
      int e = e0 + k * 256;
      if (e < N_EDGES) {
        int s = src[e], d = dst[e];
        out1[e] = e_w[e];
        atomicAdd(&cnt_out[s], 1);                              // fire-and-forget
        rank8[e] = (unsigned char)atomicAdd(&cnt_in[d], 1);     // ticket -> coalesced store
      }
    }
    return;
  }

  // -------- GEMM block: 128 rows x 128 cols, 4 waves of 64x64, barrier-free --------
  const int q = o - (o > 2 ? 1 : 0);         // 0,1 -> hs16; 2,3 -> y8
  const int t = w * 8 + r;
  if (t >= ROW_TILES) return;                // holes in the last window

  const int m0   = t * 128;
  const int bn0  = q * 128;                  // row offset into Bt [512][256]
  const int lane = tid & 63;
  const int wave = tid >> 6;
  const int wm   = (wave & 1) * 64;
  const int wn   = (wave >> 1) * 64;
  const int fr   = lane & 15;
  const int fkc  = lane >> 4;                // k-chunk 0..3 (8 elems each)

  // per-lane fragment base pointers (A rows clamped against OOB reads)
  const float* ap[4];
  const unsigned short* bp[4];
#pragma unroll
  for (int i = 0; i < 4; ++i) {
    int row = m0 + wm + i * 16 + fr;
    row = (row < N_NODES) ? row : 0;         // outputs for pad rows are discarded
    ap[i] = feature + (size_t)row * 256 + fkc * 8;
  }
#pragma unroll
  for (int j = 0; j < 4; ++j)
    bp[j] = Bt + (size_t)(bn0 + wn + j * 16 + fr) * 256 + fkc * 8;

  f32x4_t acc[4][4] = {};

  for (int s = 0; s < 8; ++s) {
    const int k0 = s * 32;
    bf16x8_t av[4], bv[4];
#pragma unroll
    for (int i = 0; i < 4; ++i) {
      float4 lo = *(const float4*)(ap[i] + k0);
      float4 hi = *(const float4*)(ap[i] + k0 + 4);
      av[i] = cvt8(lo, hi);
    }
#pragma unroll
    for (int j = 0; j < 4; ++j)
      bv[j] = *(const bf16x8_t*)(bp[j] + k0);
#pragma unroll
    for (int i = 0; i < 4; ++i)
#pragma unroll
      for (int j = 0; j < 4; ++j)
        acc[i][j] = __builtin_amdgcn_mfma_f32_16x16x32_bf16(av[i], bv[j], acc[i][j], 0, 0, 0);
  }

  // ---- epilogue: C/D layout col=lane&15, row=(lane>>4)*4+rr ----
  if (q < 2) {
    const int cbase = q * 128 + wn + (lane & 15);
#pragma unroll
    for (int i = 0; i < 4; ++i) {
      int rowb = m0 + wm + i * 16 + (lane >> 4) * 4;
#pragma unroll
      for (int j = 0; j < 4; ++j) {
        int col = cbase + j * 16;
#pragma unroll
        for (int rr = 0; rr < 4; ++rr) {
          int row = rowb + rr;
          if (row < N_NODES)
            hs16[(size_t)row * 256 + col] = f2bf(acc[i][j][rr]);
        }
      }
    }
  } else {
    const int cbase = (q - 2) * 128 + wn + (lane & 15);
#pragma unroll
    for (int i = 0; i < 4; ++i) {
      int rowb = m0 + wm + i * 16 + (lane >> 4) * 4;
#pragma unroll
      for (int j = 0; j < 4; ++j) {
        int col = cbase + j * 16;
#pragma unroll
        for (int rr = 0; rr < 4; ++rr) {
          int row = rowb + rr;
          if (row < N_NODES) {
            float ys = acc[i][j][rr];
            unsigned int pk = (unsigned int)__builtin_amdgcn_cvt_pk_fp8_f32(ys, ys, 0, false);
            y8[(size_t)row * 256 + col] = (unsigned char)(pk & 0xffu);
          }
        }
      }
    }
  }
}

// ------------- k2a: per-block sums of cnt_in (196 blocks x 256) -------------
__global__ __launch_bounds__(256) void scan1_kernel(
    const int* __restrict__ cnt, int* __restrict__ sums)
{
  int idx = blockIdx.x * 256 + threadIdx.x;
  int v = (idx < N_NODES) ? cnt[idx] : 0;
#pragma unroll
  for (int d = 32; d; d >>= 1) v += __shfl_down(v, d);
  __shared__ int sm[4];
  if ((threadIdx.x & 63) == 0) sm[threadIdx.x >> 6] = v;
  __syncthreads();
  if (threadIdx.x == 0) sums[blockIdx.x] = sm[0] + sm[1] + sm[2] + sm[3];
}

// ------------- k2b: exclusive scan of the 196 partials (1 block) -------------
__global__ __launch_bounds__(256) void scan2_kernel(int* __restrict__ sums)
{
  const int t = threadIdx.x;
  int v = (t < SCAN_BLOCKS) ? sums[t] : 0;
  __shared__ int sm[256];
  sm[t] = v;
  __syncthreads();
  for (int d = 1; d < 256; d <<= 1) {
    int u = (t >= d) ? sm[t - d] : 0;
    __syncthreads();
    sm[t] += u;
    __syncthreads();
  }
  if (t < SCAN_BLOCKS) sums[t] = sm[t] - v;   // exclusive
}

// ------------- k2c: local scan + base -> off[0..N_NODES] -------------
__global__ __launch_bounds__(256) void scan3_kernel(
    const int* __restrict__ cnt, const int* __restrict__ sums, int* __restrict__ off)
{
  const int t = threadIdx.x;
  int idx = blockIdx.x * 256 + t;
  int v = (idx < N_NODES) ? cnt[idx] : 0;
  __shared__ int sm[256];
  sm[t] = v;
  __syncthreads();
  for (int d = 1; d < 256; d <<= 1) {
    int u = (t >= d) ? sm[t - d] : 0;
    __syncthreads();
    sm[t] += u;
    __syncthreads();
  }
  if (idx <= N_NODES) off[idx] = sm[t] - v + sums[blockIdx.x];
}

// ------------- k3: atomic-free CSR scatter -------------
// csr entry: packed u32 = (bf16(w) << 16) | src_u16
__global__ __launch_bounds__(256) void scatter_kernel(
    const float* __restrict__ e_w, const int* __restrict__ src, const int* __restrict__ dst,
    const unsigned char* __restrict__ rank8, const int* __restrict__ off,
    unsigned int* __restrict__ csr)
{
  const int e0 = blockIdx.x * 1024 + threadIdx.x;
#pragma unroll
  for (int k = 0; k < 4; ++k) {
    int e = e0 + k * 256;
    if (e < N_EDGES) {
      int d = dst[e];
      int r = rank8[e];
      float w = e_w[e];
      int s = src[e];
      csr[off[d] + r] = ((unsigned int)f2bf(w) << 16) | (unsigned int)s;
    }
  }
}

// ------------- k4: aggregation from CSR: half-wave per node, 8B loads -------------
// out0[n] = hs16[n] + indeg^-1/2 * ( sum_e e_w * outdeg[s]^-1/2 * y8[s] + b )
__global__ __launch_bounds__(256) void agg_kernel(
    const unsigned char* __restrict__ y8, const unsigned int* __restrict__ csr,
    const int* __restrict__ off, const int* __restrict__ cnt_out,
    const unsigned short* __restrict__ hs16,
    const float* __restrict__ bias, float* __restrict__ out0)
{
  const int hw   = threadIdx.x >> 5;        // half-wave 0..7
  const int lane = threadIdx.x & 31;
  const int node = blockIdx.x * 8 + hw;
  if (node >= N_NODES) return;
  const int base = off[node];
  const int deg  = off[node + 1] - base;

  float a0 = 0.f, a1 = 0.f, a2 = 0.f, a3 = 0.f;
  float a4 = 0.f, a5 = 0.f, a6 = 0.f, a7 = 0.f;

  for (int bb = 0; bb < deg; bb += 32) {
    int idx = bb + lane;
    unsigned int ent = (idx < deg) ? csr[base + idx] : 0u;
    int   sl = (int)(ent & 0xffffu);
    float wl = bf2f((unsigned short)(ent >> 16));   // 0 for idle lanes
    int co = cnt_out[sl]; if (co < 1) co = 1;       // fold outdeg^-1/2 (L2-resident gather)
    wl *= rsqrtf((float)co);

#pragma unroll
    for (int t0 = 0; t0 < 32; t0 += 16) {
      if (bb + t0 >= deg) break;
#pragma unroll
      for (int t = 0; t < 16; ++t) {
        int eb = t0 + t;
        int   s = __shfl(sl, eb, 32);
        float w = __shfl(wl, eb, 32);               // 0 beyond deg
        uint2 u = *(const uint2*)(y8 + (size_t)s * 256 + lane * 8);
        a0 += w * __builtin_amdgcn_cvt_f32_fp8(u.x, 0);
        a1 += w * __builtin_amdgcn_cvt_f32_fp8(u.x, 1);
        a2 += w * __builtin_amdgcn_cvt_f32_fp8(u.x, 2);
        a3 += w * __builtin_amdgcn_cvt_f32_fp8(u.x, 3);
        a4 += w * __builtin_amdgcn_cvt_f32_fp8(u.y, 0);
        a5 += w * __builtin_amdgcn_cvt_f32_fp8(u.y, 1);
        a6 += w * __builtin_amdgcn_cvt_f32_fp8(u.y, 2);
        a7 += w * __builtin_amdgcn_cvt_f32_fp8(u.y, 3);
      }
    }
  }

  int dn = deg < 1 ? 1 : deg;
  float inv = rsqrtf((float)dn);
  size_t offo = (size_t)node * 256 + lane * 8;
  u16x8 hv = *(const u16x8*)(hs16 + offo);
  float4 b0 = *(const float4*)(bias + lane * 8);
  float4 b1 = *(const float4*)(bias + lane * 8 + 4);
  float4 o0, o1;
  o0.x = bf2f(hv[0]) + (a0 + b0.x) * inv;
  o0.y = bf2f(hv[1]) + (a1 + b0.y) * inv;
  o0.z = bf2f(hv[2]) + (a2 + b0.z) * inv;
  o0.w = bf2f(hv[3]) + (a3 + b0.w) * inv;
  o1.x = bf2f(hv[4]) + (a4 + b1.x) * inv;
  o1.y = bf2f(hv[5]) + (a5 + b1.y) * inv;
  o1.z = bf2f(hv[6]) + (a6 + b1.z) * inv;
  o1.w = bf2f(hv[7]) + (a7 + b1.w) * inv;
  *(float4*)(out0 + offo)     = o0;
  *(float4*)(out0 + offo + 4) = o1;
}

extern "C" void kernel_launch(void* const* d_in, const int* in_sizes, int n_in,
                              void* d_out, int out_size, void* d_ws, size_t ws_size,
                              hipStream_t stream) {
  const float* feature = (const float*)d_in[0];
  const float* e_w     = (const float*)d_in[1];
  // d_in[2] snorm_n, d_in[3] snorm_e unused by reference
  const float* W_self  = (const float*)d_in[4];
  const float* W       = (const float*)d_in[5];
  const float* bias    = (const float*)d_in[6];
  const int*   src     = (const int*)d_in[7];
  const int*   dst     = (const int*)d_in[8];

  float* out0 = (float*)d_out;
  float* out1 = out0 + (size_t)N_NODES * 256;

  char* ws = (char*)d_ws;
  int*            cnt_in  = (int*)(ws + 0);                     // 200 KB (reserve 256 KB)
  int*            cnt_out = (int*)(ws + 262144);                // 200 KB (reserve 256 KB)
  int*            off     = (int*)(ws + 524288);                // 200 KB (reserve 256 KB)
  unsigned char*  rank8   = (unsigned char*)(ws + 786432);      // 800 KB
  int*            sums    = (int*)(ws + 1638400);               // 784 B
  unsigned int*   csr     = (unsigned int*)(ws + 1835008);      // 3.2 MB
  unsigned short* Bt      = (unsigned short*)(ws + 5242880);    // 256 KB
  unsigned char*  y8      = (unsigned char*)(ws + 5767168);     // 12.8 MB
  unsigned short* hs16    = (unsigned short*)(ws + 18567168);   // 25.6 MB
  // total ~44.2 MB

  hipMemsetAsync(ws, 0, 524288, stream);   // zero cnt_in + cnt_out

  wconv_kernel<<<WCONV_BLOCKS, 256, 0, stream>>>(W_self, W, Bt);
  gemm_edge_kernel<<<K1_BLOCKS, 256, 0, stream>>>(
      feature, Bt, e_w, src, dst, cnt_in, cnt_out, rank8, out1, hs16, y8);
  scan1_kernel<<<SCAN_BLOCKS, 256, 0, stream>>>(cnt_in, sums);
  scan2_kernel<<<1, 256, 0, stream>>>(sums);
  scan3_kernel<<<SCAN_BLOCKS, 256, 0, stream>>>(cnt_in, sums, off);
  scatter_kernel<<<EDGE_BLOCKS, 256, 0, stream>>>(e_w, src, dst, rank8, off, csr);
  agg_kernel<<<(N_NODES + 7) / 8, 256, 0, stream>>>(y8, csr, off, cnt_out, hs16, bias, out0);
}

// Round 7
// 289.980 us; speedup vs baseline: 1.0512x; 1.0512x over previous
//
#include <hip/hip_runtime.h>
#include <hip/hip_bf16.h>

#define N_NODES 50000
#define N_EDGES 800000

#define ROW_TILES    391   // ceil(50000/128)
// k1 grid: 49 windows x 48 blocks. o=(b%48)>>3 in 0..5; o in {2,5} -> hist block,
// o in {0,1,3,4} -> gemm quarter q of tile t=w*8+(b&7). All 4 quarters of a tile
// share b%8 (same XCD under round-robin) -> feature L2/L3 reuse (validated R5/R6).
#define K1_BLOCKS    2352  // 49*48
#define WCONV_BLOCKS 512
#define SCAN_BLOCKS  196   // ceil(50000/256)
#define EDGE_BLOCKS  782

typedef __bf16 bf16x8_t __attribute__((ext_vector_type(8)));
typedef float  f32x4_t  __attribute__((ext_vector_type(4)));
typedef unsigned short u16x8 __attribute__((ext_vector_type(8)));
typedef unsigned int   u32x4 __attribute__((ext_vector_type(4)));

__device__ __forceinline__ unsigned short f2bf(float x) {
  __hip_bfloat16 h = __float2bfloat16(x);
  return __builtin_bit_cast(unsigned short, h);
}
__device__ __forceinline__ float bf2f(unsigned short u) {
  unsigned int v = ((unsigned int)u) << 16;
  return __builtin_bit_cast(float, v);
}
__device__ __forceinline__ unsigned int pk2(float lo, float hi) {
  return ((unsigned int)f2bf(hi) << 16) | (unsigned int)f2bf(lo);
}
__device__ __forceinline__ bf16x8_t cvt8(float4 lo, float4 hi) {
  u32x4 u;
  u.x = pk2(lo.x, lo.y); u.y = pk2(lo.z, lo.w);
  u.z = pk2(hi.x, hi.y); u.w = pk2(hi.z, hi.w);
  return __builtin_bit_cast(bf16x8_t, u);
}

// ------------- k0: W_self|W (f32, k-major) -> Bt (bf16, n-major) -------------
__global__ __launch_bounds__(256) void wconv_kernel(
    const float* __restrict__ Wself, const float* __restrict__ W,
    unsigned short* __restrict__ Bt)
{
  int idx = blockIdx.x * 256 + threadIdx.x;   // [512][256]
  int n = idx >> 8, k = idx & 255;
  float v = (n < 256) ? Wself[k * 256 + n] : W[k * 256 + (n - 256)];
  Bt[idx] = f2bf(v);
}

// ------------- k1: fused single-barrier GEMM + interleaved edge histogram -------------
// GEMM: whole B quarter-panel (64KB) -> LDS once (swizzled); ALL A fragments for the
// full K loaded to registers (MLP=64/lane, f32->bf16 in-reg); ONE __syncthreads; then
// 128 MFMAs with zero further global dependency. One latency exposure per block.
__global__ __launch_bounds__(256, 2) void gemm_edge_kernel(
    const float* __restrict__ feature,       // [N][256] f32
    const unsigned short* __restrict__ Bt,   // [512][256] bf16 (n-major)
    const float* __restrict__ e_w, const int* __restrict__ src, const int* __restrict__ dst,
    int* __restrict__ cnt_in, int* __restrict__ cnt_out,
    unsigned char* __restrict__ rank8, float* __restrict__ out1,
    unsigned short* __restrict__ hs16,       // [N][256] bf16 (feature@Wself)
    unsigned char* __restrict__ y8)          // [N][256] fp8 e4m3 (feature@W, un-normalized)
{
  const int b   = blockIdx.x;
  const int tid = threadIdx.x;
  const int w   = b / 48;
  const int o   = (b % 48) >> 3;             // 0..5
  const int r   = b & 7;

  if (o == 2 || o == 5) {
    // -------- hist block: 1024 edges, 4 per thread, coalesced; NO scatter --------
    const int h = w * 16 + r + ((o == 5) ? 8 : 0);
    if (h >= EDGE_BLOCKS) return;
    const int e0 = h * 1024 + tid;
#pragma unroll
    for (int k = 0; k < 4; ++k) {
      int e = e0 + k * 256;
      if (e < N_EDGES) {
        int s = src[e], d = dst[e];
        out1[e] = e_w[e];
        atomicAdd(&cnt_out[s], 1);                              // fire-and-forget
        rank8[e] = (unsigned char)atomicAdd(&cnt_in[d], 1);     // ticket -> coalesced store
      }
    }
    return;
  }

  // -------- GEMM block: 128 rows x 128 cols, 4 waves of 64x64, single barrier --------
  __shared__ __align__(16) unsigned short Bs[128 * 256];   // 64KB, XOR-swizzled 16B chunks

  const int q = o - (o > 2 ? 1 : 0);         // 0,1 -> hs16; 2,3 -> y8
  const int t = w * 8 + r;
  if (t >= ROW_TILES) return;                // holes in last window (uniform, pre-barrier)

  const int m0   = t * 128;
  const int bn0  = q * 128;                  // row offset into Bt [512][256]
  const int lane = tid & 63;
  const int wave = tid >> 6;
  const int wm   = (wave & 1) * 64;
  const int wn   = (wave >> 1) * 64;
  const int fr   = lane & 15;
  const int fkc  = lane >> 4;                // k-chunk within 32-k step (8 elems each)

  // ---- stage whole B panel: 16 x global_load_lds(16B) per thread, issued FIRST ----
  // LDS chunk slot cs of row rr holds global chunk cs ^ (rr&7)  (bank-despread on read)
#pragma unroll
  for (int m = 0; m < 16; ++m) {
    int L  = m * 256 + tid;                  // 16B-slot index 0..4095 (lane-contiguous)
    int rr = L >> 5, cs = L & 31;
    int cg = cs ^ (rr & 7);
    const unsigned short* gb = Bt + (size_t)(bn0 + rr) * 256 + cg * 8;
    __builtin_amdgcn_global_load_lds((const __attribute__((address_space(1))) void*)gb,
                                     (__attribute__((address_space(3))) void*)&Bs[(size_t)L * 8],
                                     16, 0, 0);
  }

  // ---- load + convert ALL A fragments for full K (overlaps B's LDS fill) ----
  const float* ap[4];
#pragma unroll
  for (int i = 0; i < 4; ++i) {
    int row = m0 + wm + i * 16 + fr;
    row = (row < N_NODES) ? row : 0;         // pad-row outputs discarded
    ap[i] = feature + (size_t)row * 256 + fkc * 8;
  }
  bf16x8_t Areg[8][4];
#pragma unroll
  for (int s = 0; s < 8; ++s)
#pragma unroll
    for (int i = 0; i < 4; ++i) {
      float4 lo = *(const float4*)(ap[i] + s * 32);
      float4 hi = *(const float4*)(ap[i] + s * 32 + 4);
      Areg[s][i] = cvt8(lo, hi);
    }

  __syncthreads();                           // the ONLY barrier

  f32x4_t acc[4][4] = {};
#pragma unroll
  for (int s = 0; s < 8; ++s) {
    bf16x8_t bv[4];
#pragma unroll
    for (int j = 0; j < 4; ++j) {
      int R  = wn + j * 16 + fr;
      int cs = (s * 4 + fkc) ^ (R & 7);
      bv[j] = *(const bf16x8_t*)&Bs[R * 256 + cs * 8];
    }
#pragma unroll
    for (int i = 0; i < 4; ++i)
#pragma unroll
      for (int j = 0; j < 4; ++j)
        acc[i][j] = __builtin_amdgcn_mfma_f32_16x16x32_bf16(Areg[s][i], bv[j], acc[i][j], 0, 0, 0);
  }

  // ---- epilogue: C/D layout col=lane&15, row=(lane>>4)*4+rr ----
  if (q < 2) {
    const int cbase = q * 128 + wn + (lane & 15);
#pragma unroll
    for (int i = 0; i < 4; ++i) {
      int rowb = m0 + wm + i * 16 + (lane >> 4) * 4;
#pragma unroll
      for (int j = 0; j < 4; ++j) {
        int col = cbase + j * 16;
#pragma unroll
        for (int rr = 0; rr < 4; ++rr) {
          int row = rowb + rr;
          if (row < N_NODES)
            hs16[(size_t)row * 256 + col] = f2bf(acc[i][j][rr]);
        }
      }
    }
  } else {
    const int cbase = (q - 2) * 128 + wn + (lane & 15);
#pragma unroll
    for (int i = 0; i < 4; ++i) {
      int rowb = m0 + wm + i * 16 + (lane >> 4) * 4;
#pragma unroll
      for (int j = 0; j < 4; ++j) {
        int col = cbase + j * 16;
#pragma unroll
        for (int rr = 0; rr < 4; ++rr) {
          int row = rowb + rr;
          if (row < N_NODES) {
            float ys = acc[i][j][rr];
            unsigned int pk = (unsigned int)__builtin_amdgcn_cvt_pk_fp8_f32(ys, ys, 0, false);
            y8[(size_t)row * 256 + col] = (unsigned char)(pk & 0xffu);
          }
        }
      }
    }
  }
}

// ------------- k2a: per-block sums of cnt_in (196 blocks x 256) -------------
__global__ __launch_bounds__(256) void scan1_kernel(
    const int* __restrict__ cnt, int* __restrict__ sums)
{
  int idx = blockIdx.x * 256 + threadIdx.x;
  int v = (idx < N_NODES) ? cnt[idx] : 0;
#pragma unroll
  for (int d = 32; d; d >>= 1) v += __shfl_down(v, d);
  __shared__ int sm[4];
  if ((threadIdx.x & 63) == 0) sm[threadIdx.x >> 6] = v;
  __syncthreads();
  if (threadIdx.x == 0) sums[blockIdx.x] = sm[0] + sm[1] + sm[2] + sm[3];
}

// ------------- k2b: exclusive scan of the 196 partials (1 block) -------------
__global__ __launch_bounds__(256) void scan2_kernel(int* __restrict__ sums)
{
  const int t = threadIdx.x;
  int v = (t < SCAN_BLOCKS) ? sums[t] : 0;
  __shared__ int sm[256];
  sm[t] = v;
  __syncthreads();
  for (int d = 1; d < 256; d <<= 1) {
    int u = (t >= d) ? sm[t - d] : 0;
    __syncthreads();
    sm[t] += u;
    __syncthreads();
  }
  if (t < SCAN_BLOCKS) sums[t] = sm[t] - v;   // exclusive
}

// ------------- k2c: local scan + base -> off[0..N_NODES] -------------
__global__ __launch_bounds__(256) void scan3_kernel(
    const int* __restrict__ cnt, const int* __restrict__ sums, int* __restrict__ off)
{
  const int t = threadIdx.x;
  int idx = blockIdx.x * 256 + t;
  int v = (idx < N_NODES) ? cnt[idx] : 0;
  __shared__ int sm[256];
  sm[t] = v;
  __syncthreads();
  for (int d = 1; d < 256; d <<= 1) {
    int u = (t >= d) ? sm[t - d] : 0;
    __syncthreads();
    sm[t] += u;
    __syncthreads();
  }
  if (idx <= N_NODES) off[idx] = sm[t] - v + sums[blockIdx.x];
}

// ------------- k3: atomic-free CSR scatter, outdeg^-1/2 PRE-FOLDED into weight -------------
// csr entry: packed u32 = (bf16(e_w * outdeg^-1/2) << 16) | src_u16
__global__ __launch_bounds__(256) void scatter_kernel(
    const float* __restrict__ e_w, const int* __restrict__ src, const int* __restrict__ dst,
    const unsigned char* __restrict__ rank8, const int* __restrict__ off,
    const int* __restrict__ cnt_out, unsigned int* __restrict__ csr)
{
  const int e0 = blockIdx.x * 1024 + threadIdx.x;
#pragma unroll
  for (int k = 0; k < 4; ++k) {
    int e = e0 + k * 256;
    if (e < N_EDGES) {
      int d = dst[e];
      int r = rank8[e];
      int s = src[e];
      int co = cnt_out[s]; if (co < 1) co = 1;        // L2-hot 200KB gather
      float w = e_w[e] * rsqrtf((float)co);
      csr[off[d] + r] = ((unsigned int)f2bf(w) << 16) | (unsigned int)s;
    }
  }
}

// ------------- k4: aggregation from CSR: half-wave per node, 8B loads -------------
// out0[n] = hs16[n] + indeg^-1/2 * ( sum_e w' * y8[s] + b ),  w' pre-folded
__global__ __launch_bounds__(256) void agg_kernel(
    const unsigned char* __restrict__ y8, const unsigned int* __restrict__ csr,
    const int* __restrict__ off, const unsigned short* __restrict__ hs16,
    const float* __restrict__ bias, float* __restrict__ out0)
{
  const int hw   = threadIdx.x >> 5;        // half-wave 0..7
  const int lane = threadIdx.x & 31;
  const int node = blockIdx.x * 8 + hw;
  if (node >= N_NODES) return;
  const int base = off[node];
  const int deg  = off[node + 1] - base;

  float a0 = 0.f, a1 = 0.f, a2 = 0.f, a3 = 0.f;
  float a4 = 0.f, a5 = 0.f, a6 = 0.f, a7 = 0.f;

  for (int bb = 0; bb < deg; bb += 32) {
    int idx = bb + lane;
    unsigned int ent = (idx < deg) ? csr[base + idx] : 0u;
    int   sl = (int)(ent & 0xffffu);
    float wl = bf2f((unsigned short)(ent >> 16));   // 0 for idle lanes (pre-normalized)

#pragma unroll
    for (int t0 = 0; t0 < 32; t0 += 8) {
      if (bb + t0 >= deg) break;                    // uniform per half-wave
#pragma unroll
      for (int t = 0; t < 8; ++t) {
        int eb = t0 + t;
        int   s = __shfl(sl, eb, 32);
        float w = __shfl(wl, eb, 32);               // 0 beyond deg
        uint2 u = *(const uint2*)(y8 + (size_t)s * 256 + lane * 8);
        a0 += w * __builtin_amdgcn_cvt_f32_fp8(u.x, 0);
        a1 += w * __builtin_amdgcn_cvt_f32_fp8(u.x, 1);
        a2 += w * __builtin_amdgcn_cvt_f32_fp8(u.x, 2);
        a3 += w * __builtin_amdgcn_cvt_f32_fp8(u.x, 3);
        a4 += w * __builtin_amdgcn_cvt_f32_fp8(u.y, 0);
        a5 += w * __builtin_amdgcn_cvt_f32_fp8(u.y, 1);
        a6 += w * __builtin_amdgcn_cvt_f32_fp8(u.y, 2);
        a7 += w * __builtin_amdgcn_cvt_f32_fp8(u.y, 3);
      }
    }
  }

  int dn = deg < 1 ? 1 : deg;
  float inv = rsqrtf((float)dn);
  size_t offo = (size_t)node * 256 + lane * 8;
  u16x8 hv = *(const u16x8*)(hs16 + offo);
  float4 b0 = *(const float4*)(bias + lane * 8);
  float4 b1 = *(const float4*)(bias + lane * 8 + 4);
  float4 o0, o1;
  o0.x = bf2f(hv[0]) + (a0 + b0.x) * inv;
  o0.y = bf2f(hv[1]) + (a1 + b0.y) * inv;
  o0.z = bf2f(hv[2]) + (a2 + b0.z) * inv;
  o0.w = bf2f(hv[3]) + (a3 + b0.w) * inv;
  o1.x = bf2f(hv[4]) + (a4 + b1.x) * inv;
  o1.y = bf2f(hv[5]) + (a5 + b1.y) * inv;
  o1.z = bf2f(hv[6]) + (a6 + b1.z) * inv;
  o1.w = bf2f(hv[7]) + (a7 + b1.w) * inv;
  *(float4*)(out0 + offo)     = o0;
  *(float4*)(out0 + offo + 4) = o1;
}

extern "C" void kernel_launch(void* const* d_in, const int* in_sizes, int n_in,
                              void* d_out, int out_size, void* d_ws, size_t ws_size,
                              hipStream_t stream) {
  const float* feature = (const float*)d_in[0];
  const float* e_w     = (const float*)d_in[1];
  // d_in[2] snorm_n, d_in[3] snorm_e unused by reference
  const float* W_self  = (const float*)d_in[4];
  const float* W       = (const float*)d_in[5];
  const float* bias    = (const float*)d_in[6];
  const int*   src     = (const int*)d_in[7];
  const int*   dst     = (const int*)d_in[8];

  float* out0 = (float*)d_out;
  float* out1 = out0 + (size_t)N_NODES * 256;

  char* ws = (char*)d_ws;
  int*            cnt_in  = (int*)(ws + 0);                     // 200 KB (reserve 256 KB)
  int*            cnt_out = (int*)(ws + 262144);                // 200 KB (reserve 256 KB)
  int*            off     = (int*)(ws + 524288);                // 200 KB (reserve 256 KB)
  unsigned char*  rank8   = (unsigned char*)(ws + 786432);      // 800 KB
  int*            sums    = (int*)(ws + 1638400);               // 784 B
  unsigned int*   csr     = (unsigned int*)(ws + 1835008);      // 3.2 MB
  unsigned short* Bt      = (unsigned short*)(ws + 5242880);    // 256 KB
  unsigned char*  y8      = (unsigned char*)(ws + 5767168);     // 12.8 MB
  unsigned short* hs16    = (unsigned short*)(ws + 18567168);   // 25.6 MB
  // total ~44.2 MB

  hipMemsetAsync(ws, 0, 524288, stream);   // zero cnt_in + cnt_out

  wconv_kernel<<<WCONV_BLOCKS, 256, 0, stream>>>(W_self, W, Bt);
  gemm_edge_kernel<<<K1_BLOCKS, 256, 0, stream>>>(
      feature, Bt, e_w, src, dst, cnt_in, cnt_out, rank8, out1, hs16, y8);
  scan1_kernel<<<SCAN_BLOCKS, 256, 0, stream>>>(cnt_in, sums);
  scan2_kernel<<<1, 256, 0, stream>>>(sums);
  scan3_kernel<<<SCAN_BLOCKS, 256, 0, stream>>>(cnt_in, sums, off);
  scatter_kernel<<<EDGE_BLOCKS, 256, 0, stream>>>(e_w, src, dst, rank8, off, cnt_out, csr);
  agg_kernel<<<(N_NODES + 7) / 8, 256, 0, stream>>>(y8, csr, off, hs16, bias, out0);
}

// Round 8
// 254.465 us; speedup vs baseline: 1.1979x; 1.1396x over previous
//
#include <hip/hip_runtime.h>
#include <hip/hip_bf16.h>

#define N_NODES 50000
#define N_EDGES 800000

#define ROW_TILES    391   // ceil(50000/128)
// k1 grid: 49 windows x 48 blocks. p=b%48. hist iff p%3==2 (identical global pattern
// to R4's b%3==2, since 48%3==0 -> preserves the 96us schedule). gemm slots: c=p>>3,
// r=p&7 -> tile t=w*8+r, quarter q = rank of c among gemm-c's for this r. All 4
// quarters of t share b%8==r (same XCD under round-robin, validated R5/R6: FETCH -45MB).
#define K1_BLOCKS    2352  // 49*48
#define WCONV_BLOCKS 512
#define SCAN_BLOCKS  196   // ceil(50000/256)
#define EDGE_BLOCKS  782

typedef __bf16 bf16x8_t __attribute__((ext_vector_type(8)));
typedef float  f32x4_t  __attribute__((ext_vector_type(4)));
typedef unsigned short u16x8 __attribute__((ext_vector_type(8)));

__device__ __forceinline__ unsigned short f2bf(float x) {
  __hip_bfloat16 h = __float2bfloat16(x);
  return __builtin_bit_cast(unsigned short, h);
}
__device__ __forceinline__ float bf2f(unsigned short u) {
  unsigned int v = ((unsigned int)u) << 16;
  return __builtin_bit_cast(float, v);
}
__device__ __forceinline__ unsigned int pk2(float lo, float hi) {
  return ((unsigned int)f2bf(hi) << 16) | (unsigned int)f2bf(lo);
}

// ------------- k0: W_self|W (f32, k-major) -> Bt (bf16, n-major) -------------
__global__ __launch_bounds__(256) void wconv_kernel(
    const float* __restrict__ Wself, const float* __restrict__ W,
    unsigned short* __restrict__ Bt)
{
  int idx = blockIdx.x * 256 + threadIdx.x;   // [512][256]
  int n = idx >> 8, k = idx & 255;
  float v = (n < 256) ? Wself[k * 256 + n] : W[k * 256 + (n - 256)];
  Bt[idx] = f2bf(v);
}

// ------------- k1: R4's pipelined GEMM (96us schedule) + XCD-affine tiles + hist -------------
// GEMM: 128x128 tile, 4 waves of 64x64, BK=32 double-buffered, 32KB LDS -> 4 blocks/CU,
// prefetch-before-compute, addr-swizzled A ds_write + pre-swizzled B global_load_lds
// (0 bank conflicts, measured R4). Epilogue: hs16 bf16 / y8 fp8 (un-normalized).
__global__ __launch_bounds__(256, 4) void gemm_edge_kernel(
    const float* __restrict__ feature,       // [N][256] f32
    const unsigned short* __restrict__ Bt,   // [512][256] bf16 (n-major)
    const float* __restrict__ e_w, const int* __restrict__ src, const int* __restrict__ dst,
    int* __restrict__ cnt_in, int* __restrict__ cnt_out,
    unsigned char* __restrict__ rank8, float* __restrict__ out1,
    unsigned short* __restrict__ hs16,       // [N][256] bf16 (feature@Wself)
    unsigned char* __restrict__ y8)          // [N][256] fp8 e4m3 (feature@W, un-normalized)
{
  const int b   = blockIdx.x;
  const int tid = threadIdx.x;
  const int p   = b % 48;
  const int w   = b / 48;

  if (p % 3 == 2) {
    // -------- hist block: 1024 edges, 4 per thread, coalesced; NO scatter --------
    const int h = w * 16 + p / 3;
    if (h >= EDGE_BLOCKS) return;
    const int e0 = h * 1024 + tid;
#pragma unroll
    for (int k = 0; k < 4; ++k) {
      int e = e0 + k * 256;
      if (e < N_EDGES) {
        int s = src[e], d = dst[e];
        out1[e] = e_w[e];
        atomicAdd(&cnt_out[s], 1);                              // fire-and-forget
        rank8[e] = (unsigned char)atomicAdd(&cnt_in[d], 1);     // ticket -> coalesced store
      }
    }
    return;
  }

  // -------- GEMM block --------
  __shared__ __align__(16) unsigned short As[2][128 * 32];
  __shared__ __align__(16) unsigned short Bs[2][128 * 32];

  const int c = p >> 3, r = p & 7;
  int q = 0;                                  // rank of c among gemm-c's for residue r
#pragma unroll
  for (int cc = 0; cc < 6; ++cc)
    if (cc < c && (((8 * cc + r) % 3) != 2)) ++q;
  const int t = w * 8 + r;
  if (t >= ROW_TILES) return;                 // uniform per block, pre-barrier

  const int m0   = t * 128;
  const int bn0  = q * 128;                  // row offset into Bt [512][256]; q 0,1->hs16 2,3->y8
  const int lane = tid & 63;
  const int wave = tid >> 6;
  const int wm   = (wave & 1) * 64;
  const int wn   = (wave >> 1) * 64;
  const int fr   = lane & 15;
  const int fkc  = lane >> 4;                // k-chunk 0..3 (8 bf16 each)

  // A staging: thread -> row ra, global 64B slice [ha*16, ha*16+16) floats
  const int ra = tid >> 1, ha = tid & 1;
  const int sA = (ra >> 1) & 3;
  const int arow = (m0 + ra < N_NODES) ? (m0 + ra) : 0;   // clamp OOB rows (outputs discarded)
  const float* aptr = feature + (size_t)arow * 256 + ha * 16;
  const int aw0 = ra * 32 + (((2 * ha) ^ sA) * 8);        // LDS short offsets (addr-swizzled)
  const int aw1 = ra * 32 + ((((2 * ha) | 1) ^ sA) * 8);

  f32x4_t acc[4][4] = {};

  // ---- prologue: stage k-step 0 ----
  {
#pragma unroll
    for (int i = 0; i < 2; ++i) {
      int rr = i * 64 + (tid >> 2);
      int cg = (tid & 3) ^ ((rr >> 1) & 3);
      const unsigned short* gb = Bt + (size_t)(bn0 + rr) * 256 + cg * 8;
      __builtin_amdgcn_global_load_lds((const __attribute__((address_space(1))) void*)gb,
                                       (__attribute__((address_space(3))) void*)&Bs[0][i * 2048 + wave * 512],
                                       16, 0, 0);
    }
    float4 a0 = *(const float4*)(aptr + 0);
    float4 a1 = *(const float4*)(aptr + 4);
    float4 a2 = *(const float4*)(aptr + 8);
    float4 a3 = *(const float4*)(aptr + 12);
    uint4 p0, p1;
    p0.x = pk2(a0.x, a0.y); p0.y = pk2(a0.z, a0.w);
    p0.z = pk2(a1.x, a1.y); p0.w = pk2(a1.z, a1.w);
    p1.x = pk2(a2.x, a2.y); p1.y = pk2(a2.z, a2.w);
    p1.z = pk2(a3.x, a3.y); p1.w = pk2(a3.z, a3.w);
    *(uint4*)&As[0][aw0] = p0;
    *(uint4*)&As[0][aw1] = p1;
  }
  __syncthreads();

  // ---- main loop: 8 k-steps of 32, prefetch-before-compute ----
#pragma unroll
  for (int s = 0; s < 8; ++s) {
    const int cb = s & 1, nb = cb ^ 1;
    float4 a0, a1, a2, a3;
    if (s < 7) {
      const int k0 = (s + 1) * 32;
#pragma unroll
      for (int i = 0; i < 2; ++i) {
        int rr = i * 64 + (tid >> 2);
        int cg = (tid & 3) ^ ((rr >> 1) & 3);
        const unsigned short* gb = Bt + (size_t)(bn0 + rr) * 256 + k0 + cg * 8;
        __builtin_amdgcn_global_load_lds((const __attribute__((address_space(1))) void*)gb,
                                         (__attribute__((address_space(3))) void*)&Bs[nb][i * 2048 + wave * 512],
                                         16, 0, 0);
      }
      a0 = *(const float4*)(aptr + k0 + 0);
      a1 = *(const float4*)(aptr + k0 + 4);
      a2 = *(const float4*)(aptr + k0 + 8);
      a3 = *(const float4*)(aptr + k0 + 12);
    }

    bf16x8_t af[4], bv[4];
#pragma unroll
    for (int i = 0; i < 4; ++i) {
      int R = wm + i * 16 + fr;
      af[i] = *(const bf16x8_t*)&As[cb][R * 32 + ((fkc ^ ((R >> 1) & 3)) * 8)];
    }
#pragma unroll
    for (int j = 0; j < 4; ++j) {
      int R = wn + j * 16 + fr;
      bv[j] = *(const bf16x8_t*)&Bs[cb][R * 32 + ((fkc ^ ((R >> 1) & 3)) * 8)];
    }
#pragma unroll
    for (int i = 0; i < 4; ++i)
#pragma unroll
      for (int j = 0; j < 4; ++j)
        acc[i][j] = __builtin_amdgcn_mfma_f32_16x16x32_bf16(af[i], bv[j], acc[i][j], 0, 0, 0);

    if (s < 7) {
      uint4 p0, p1;
      p0.x = pk2(a0.x, a0.y); p0.y = pk2(a0.z, a0.w);
      p0.z = pk2(a1.x, a1.y); p0.w = pk2(a1.z, a1.w);
      p1.x = pk2(a2.x, a2.y); p1.y = pk2(a2.z, a2.w);
      p1.z = pk2(a3.x, a3.y); p1.w = pk2(a3.z, a3.w);
      *(uint4*)&As[nb][aw0] = p0;
      *(uint4*)&As[nb][aw1] = p1;
      __syncthreads();
    }
  }

  // ---- epilogue: C/D layout col=lane&15, row=(lane>>4)*4+rr ----
  if (q < 2) {
    const int cbase = q * 128 + wn + (lane & 15);
#pragma unroll
    for (int i = 0; i < 4; ++i) {
      int rowb = m0 + wm + i * 16 + (lane >> 4) * 4;
#pragma unroll
      for (int j = 0; j < 4; ++j) {
        int col = cbase + j * 16;
#pragma unroll
        for (int rr = 0; rr < 4; ++rr) {
          int row = rowb + rr;
          if (row < N_NODES)
            hs16[(size_t)row * 256 + col] = f2bf(acc[i][j][rr]);
        }
      }
    }
  } else {
    const int cbase = (q - 2) * 128 + wn + (lane & 15);
#pragma unroll
    for (int i = 0; i < 4; ++i) {
      int rowb = m0 + wm + i * 16 + (lane >> 4) * 4;
#pragma unroll
      for (int j = 0; j < 4; ++j) {
        int col = cbase + j * 16;
#pragma unroll
        for (int rr = 0; rr < 4; ++rr) {
          int row = rowb + rr;
          if (row < N_NODES) {
            float ys = acc[i][j][rr];
            unsigned int pk = (unsigned int)__builtin_amdgcn_cvt_pk_fp8_f32(ys, ys, 0, false);
            y8[(size_t)row * 256 + col] = (unsigned char)(pk & 0xffu);
          }
        }
      }
    }
  }
}

// ------------- k2a: per-block sums of cnt_in (196 blocks x 256) -------------
__global__ __launch_bounds__(256) void scan1_kernel(
    const int* __restrict__ cnt, int* __restrict__ sums)
{
  int idx = blockIdx.x * 256 + threadIdx.x;
  int v = (idx < N_NODES) ? cnt[idx] : 0;
#pragma unroll
  for (int d = 32; d; d >>= 1) v += __shfl_down(v, d);
  __shared__ int sm[4];
  if ((threadIdx.x & 63) == 0) sm[threadIdx.x >> 6] = v;
  __syncthreads();
  if (threadIdx.x == 0) sums[blockIdx.x] = sm[0] + sm[1] + sm[2] + sm[3];
}

// ------------- k2b: local scan + self-computed base -> off[0..N_NODES] -------------
// base = sum(sums[0..b-1]) computed per block (196 ints, trivial) -> scan2 deleted.
__global__ __launch_bounds__(256) void scan3_kernel(
    const int* __restrict__ cnt, const int* __restrict__ sums, int* __restrict__ off)
{
  const int t = threadIdx.x;
  const int b = blockIdx.x;
  int v = (t < b) ? sums[t] : 0;            // b <= 195 < 256
#pragma unroll
  for (int d = 32; d; d >>= 1) v += __shfl_down(v, d);
  __shared__ int sm4[4];
  __shared__ int sbase;
  if ((t & 63) == 0) sm4[t >> 6] = v;
  __syncthreads();
  if (t == 0) sbase = sm4[0] + sm4[1] + sm4[2] + sm4[3];
  __syncthreads();
  const int base = sbase;

  int idx = b * 256 + t;
  int c = (idx < N_NODES) ? cnt[idx] : 0;
  __shared__ int sm[256];
  sm[t] = c;
  __syncthreads();
  for (int d = 1; d < 256; d <<= 1) {
    int u = (t >= d) ? sm[t - d] : 0;
    __syncthreads();
    sm[t] += u;
    __syncthreads();
  }
  if (idx <= N_NODES) off[idx] = sm[t] - c + base;
}

// ------------- k3: atomic-free CSR scatter, outdeg^-1/2 PRE-FOLDED into weight -------------
// csr entry: packed u32 = (bf16(e_w * outdeg^-1/2) << 16) | src_u16
__global__ __launch_bounds__(256) void scatter_kernel(
    const float* __restrict__ e_w, const int* __restrict__ src, const int* __restrict__ dst,
    const unsigned char* __restrict__ rank8, const int* __restrict__ off,
    const int* __restrict__ cnt_out, unsigned int* __restrict__ csr)
{
  const int e0 = blockIdx.x * 1024 + threadIdx.x;
#pragma unroll
  for (int k = 0; k < 4; ++k) {
    int e = e0 + k * 256;
    if (e < N_EDGES) {
      int d = dst[e];
      int r = rank8[e];
      int s = src[e];
      int co = cnt_out[s]; if (co < 1) co = 1;        // L2-hot 200KB gather
      float w = e_w[e] * rsqrtf((float)co);
      csr[off[d] + r] = ((unsigned int)f2bf(w) << 16) | (unsigned int)s;
    }
  }
}

// ------------- k4: aggregation from CSR: 16 lanes/node, 16B gathers, 8-deep MLP -------------
// out0[n] = hs16[n] + indeg^-1/2 * ( sum_e w' * y8[s] + b ),  w' pre-folded
__global__ __launch_bounds__(256) void agg_kernel(
    const unsigned char* __restrict__ y8, const unsigned int* __restrict__ csr,
    const int* __restrict__ off, const unsigned short* __restrict__ hs16,
    const float* __restrict__ bias, float* __restrict__ out0)
{
  const int qw   = threadIdx.x >> 4;        // quarter-wave 0..15
  const int lane = threadIdx.x & 15;
  const int node = blockIdx.x * 16 + qw;
  if (node >= N_NODES) return;
  const int base = off[node];
  const int deg  = off[node + 1] - base;

  float a[16];
#pragma unroll
  for (int i = 0; i < 16; ++i) a[i] = 0.f;

  for (int bb = 0; bb < deg; bb += 16) {
    int idx = bb + lane;
    unsigned int ent = (idx < deg) ? csr[base + idx] : 0u;
    int   sl = (int)(ent & 0xffffu);
    float wl = bf2f((unsigned short)(ent >> 16));   // 0 for idle lanes (pre-normalized)

#pragma unroll
    for (int t0 = 0; t0 < 16; t0 += 8) {
      if (bb + t0 >= deg) break;                    // uniform per quarter-wave
#pragma unroll
      for (int t = 0; t < 8; ++t) {
        int eb = t0 + t;
        int   s = __shfl(sl, eb, 16);
        float w = __shfl(wl, eb, 16);               // 0 beyond deg
        uint4 u = *(const uint4*)(y8 + (size_t)s * 256 + lane * 16);
        a[0]  += w * __builtin_amdgcn_cvt_f32_fp8(u.x, 0);
        a[1]  += w * __builtin_amdgcn_cvt_f32_fp8(u.x, 1);
        a[2]  += w * __builtin_amdgcn_cvt_f32_fp8(u.x, 2);
        a[3]  += w * __builtin_amdgcn_cvt_f32_fp8(u.x, 3);
        a[4]  += w * __builtin_amdgcn_cvt_f32_fp8(u.y, 0);
        a[5]  += w * __builtin_amdgcn_cvt_f32_fp8(u.y, 1);
        a[6]  += w * __builtin_amdgcn_cvt_f32_fp8(u.y, 2);
        a[7]  += w * __builtin_amdgcn_cvt_f32_fp8(u.y, 3);
        a[8]  += w * __builtin_amdgcn_cvt_f32_fp8(u.z, 0);
        a[9]  += w * __builtin_amdgcn_cvt_f32_fp8(u.z, 1);
        a[10] += w * __builtin_amdgcn_cvt_f32_fp8(u.z, 2);
        a[11] += w * __builtin_amdgcn_cvt_f32_fp8(u.z, 3);
        a[12] += w * __builtin_amdgcn_cvt_f32_fp8(u.w, 0);
        a[13] += w * __builtin_amdgcn_cvt_f32_fp8(u.w, 1);
        a[14] += w * __builtin_amdgcn_cvt_f32_fp8(u.w, 2);
        a[15] += w * __builtin_amdgcn_cvt_f32_fp8(u.w, 3);
      }
    }
  }

  int dn = deg < 1 ? 1 : deg;
  float inv = rsqrtf((float)dn);
  size_t offo = (size_t)node * 256 + lane * 16;
  u16x8 h0 = *(const u16x8*)(hs16 + offo);
  u16x8 h1 = *(const u16x8*)(hs16 + offo + 8);
  float4 b0 = *(const float4*)(bias + lane * 16);
  float4 b1 = *(const float4*)(bias + lane * 16 + 4);
  float4 b2 = *(const float4*)(bias + lane * 16 + 8);
  float4 b3 = *(const float4*)(bias + lane * 16 + 12);
  float4 o0, o1, o2, o3;
  o0.x = bf2f(h0[0]) + (a[0]  + b0.x) * inv;
  o0.y = bf2f(h0[1]) + (a[1]  + b0.y) * inv;
  o0.z = bf2f(h0[2]) + (a[2]  + b0.z) * inv;
  o0.w = bf2f(h0[3]) + (a[3]  + b0.w) * inv;
  o1.x = bf2f(h0[4]) + (a[4]  + b1.x) * inv;
  o1.y = bf2f(h0[5]) + (a[5]  + b1.y) * inv;
  o1.z = bf2f(h0[6]) + (a[6]  + b1.z) * inv;
  o1.w = bf2f(h0[7]) + (a[7]  + b1.w) * inv;
  o2.x = bf2f(h1[0]) + (a[8]  + b2.x) * inv;
  o2.y = bf2f(h1[1]) + (a[9]  + b2.y) * inv;
  o2.z = bf2f(h1[2]) + (a[10] + b2.z) * inv;
  o2.w = bf2f(h1[3]) + (a[11] + b2.w) * inv;
  o3.x = bf2f(h1[4]) + (a[12] + b3.x) * inv;
  o3.y = bf2f(h1[5]) + (a[13] + b3.y) * inv;
  o3.z = bf2f(h1[6]) + (a[14] + b3.z) * inv;
  o3.w = bf2f(h1[7]) + (a[15] + b3.w) * inv;
  *(float4*)(out0 + offo)      = o0;
  *(float4*)(out0 + offo + 4)  = o1;
  *(float4*)(out0 + offo + 8)  = o2;
  *(float4*)(out0 + offo + 12) = o3;
}

extern "C" void kernel_launch(void* const* d_in, const int* in_sizes, int n_in,
                              void* d_out, int out_size, void* d_ws, size_t ws_size,
                              hipStream_t stream) {
  const float* feature = (const float*)d_in[0];
  const float* e_w     = (const float*)d_in[1];
  // d_in[2] snorm_n, d_in[3] snorm_e unused by reference
  const float* W_self  = (const float*)d_in[4];
  const float* W       = (const float*)d_in[5];
  const float* bias    = (const float*)d_in[6];
  const int*   src     = (const int*)d_in[7];
  const int*   dst     = (const int*)d_in[8];

  float* out0 = (float*)d_out;
  float* out1 = out0 + (size_t)N_NODES * 256;

  char* ws = (char*)d_ws;
  int*            cnt_in  = (int*)(ws + 0);                     // 200 KB (reserve 256 KB)
  int*            cnt_out = (int*)(ws + 262144);                // 200 KB (reserve 256 KB)
  int*            off     = (int*)(ws + 524288);                // 200 KB (reserve 256 KB)
  unsigned char*  rank8   = (unsigned char*)(ws + 786432);      // 800 KB
  int*            sums    = (int*)(ws + 1638400);               // 784 B
  unsigned int*   csr     = (unsigned int*)(ws + 1835008);      // 3.2 MB
  unsigned short* Bt      = (unsigned short*)(ws + 5242880);    // 256 KB
  unsigned char*  y8      = (unsigned char*)(ws + 5767168);     // 12.8 MB
  unsigned short* hs16    = (unsigned short*)(ws + 18567168);   // 25.6 MB
  // total ~44.2 MB

  hipMemsetAsync(ws, 0, 524288, stream);   // zero cnt_in + cnt_out

  wconv_kernel<<<WCONV_BLOCKS, 256, 0, stream>>>(W_self, W, Bt);
  gemm_edge_kernel<<<K1_BLOCKS, 256, 0, stream>>>(
      feature, Bt, e_w, src, dst, cnt_in, cnt_out, rank8, out1, hs16, y8);
  scan1_kernel<<<SCAN_BLOCKS, 256, 0, stream>>>(cnt_in, sums);
  scan3_kernel<<<SCAN_BLOCKS, 256, 0, stream>>>(cnt_in, sums, off);
  scatter_kernel<<<EDGE_BLOCKS, 256, 0, stream>>>(e_w, src, dst, rank8, off, cnt_out, csr);
  agg_kernel<<<(N_NODES + 15) / 16, 256, 0, stream>>>(y8, csr, off, hs16, bias, out0);
}